// Round 4
// baseline (277.162 us; speedup 1.0000x reference)
//
#include <hip/hip_runtime.h>

#define EMBED 4096
#define NHEADS 32
#define HDIM 128
#define MAXLEN 4096
#define BATCH 8
#define NSPLIT 16

typedef float __attribute__((ext_vector_type(4))) f32x4;

// ---------------- GEMM: out[m][n] = sum_k X[m][k]*W[n][k] + bias[n], m in [0,8) ----
// 256-thread blocks (4 waves), RPW rows per wave. No LDS: x is 128 KB, L2-resident.
// W loads are nontemporal (read-once stream) to preserve K/V in L2/L3.
template<int RPW>
__device__ __forceinline__ void gemm8_body(const float* __restrict__ X,
                                           const float* __restrict__ W,
                                           const float* __restrict__ bias,
                                           float* __restrict__ out, int n)
{
    const int lane = threadIdx.x & 63;

    float acc[RPW][8];
    #pragma unroll
    for (int j = 0; j < RPW; ++j)
        #pragma unroll
        for (int m = 0; m < 8; ++m) acc[j][m] = 0.f;

    const float* wb = W + (size_t)n * EMBED;

    #pragma unroll 2
    for (int i = 0; i < 16; ++i) {
        int c = i * 256 + lane * 4;
        f32x4 wv[RPW];
        #pragma unroll
        for (int j = 0; j < RPW; ++j)
            wv[j] = __builtin_nontemporal_load((const f32x4*)(wb + (size_t)j * EMBED + c));
        #pragma unroll
        for (int m = 0; m < 8; ++m) {
            f32x4 xv = *(const f32x4*)(X + (size_t)m * EMBED + c);
            #pragma unroll
            for (int j = 0; j < RPW; ++j) {
                acc[j][m] += xv.x * wv[j].x + xv.y * wv[j].y
                           + xv.z * wv[j].z + xv.w * wv[j].w;
            }
        }
    }

    #pragma unroll
    for (int j = 0; j < RPW; ++j)
        #pragma unroll
        for (int m = 0; m < 8; ++m) {
            float v = acc[j][m];
            #pragma unroll
            for (int off = 32; off > 0; off >>= 1) v += __shfl_xor(v, off, 64);
            if (lane == 0) out[(size_t)m * EMBED + n + j] = v + bias[n + j];
        }
}

__global__ __launch_bounds__(256)
void qkv_kernel(const float* __restrict__ x,
                const float* __restrict__ Wq, const float* __restrict__ bq,
                const float* __restrict__ Wk, const float* __restrict__ bk,
                const float* __restrict__ Wv, const float* __restrict__ bv,
                float* __restrict__ qkv /* [3][8][4096] */)
{
    const int wave = threadIdx.x >> 6;
    int ng = blockIdx.x * 16 + wave * 4;     // global row among 3*4096
    int proj = ng >> 12;
    int n = ng & 4095;
    const float* W = proj == 0 ? Wq : (proj == 1 ? Wk : Wv);
    const float* b = proj == 0 ? bq : (proj == 1 ? bk : bv);
    float* out = qkv + (size_t)proj * (BATCH * EMBED);
    gemm8_body<4>(x, W, b, out, n);
}

__global__ __launch_bounds__(256)
void out_kernel(const float* __restrict__ attn,
                const float* __restrict__ Wo, const float* __restrict__ bo,
                float* __restrict__ out)
{
    const int wave = threadIdx.x >> 6;
    int n = blockIdx.x * 8 + wave * 2;
    gemm8_body<2>(attn, Wo, bo, out, n);
}

// ------------- flash-decode attention: single-pass online softmax ----------------
// Block = 256 threads = 4 waves = 8 half-wave "groups" of 32 lanes.
// Group g handles keys t = tstart + g + 8u + 32j. Batched (4-key) online update;
// register double-buffered K/V loads on the full-chunk fast path.
__global__ __launch_bounds__(256, 4)
void attn_partial(const float* __restrict__ qkv,
                  const float* __restrict__ kc, const float* __restrict__ vc,
                  const int* __restrict__ clp,
                  float* __restrict__ part_acc,   // [256][NSPLIT][128]
                  float* __restrict__ part_ms)    // [256][NSPLIT][2]
{
    __shared__ float accs[8][HDIM];
    __shared__ float mls[8][2];

    const int cl = *clp;
    const int T  = cl + 1;
    const int CH = (T + NSPLIT - 1) / NSPLIT;

    const int bh = blockIdx.x & 255;
    const int sp = blockIdx.x >> 8;
    const int b  = bh >> 5;
    const int h  = bh & 31;
    const int tid = threadIdx.x, w = tid >> 6, lane = tid & 63;
    const int half = lane >> 5, col4 = lane & 31;
    const int g = w * 2 + half;

    const int tstart = sp * CH;
    const int tend   = min(T, tstart + CH);
    const int len    = tend - tstart;

    const float* q    = qkv + (size_t)b * EMBED + h * HDIM;
    const float* knew = qkv + (size_t)BATCH * EMBED     + (size_t)b * EMBED + h * HDIM;
    const float* vnew = qkv + (size_t)2 * BATCH * EMBED + (size_t)b * EMBED + h * HDIM;
    const float* K = kc + (size_t)bh * MAXLEN * HDIM + col4 * 4;
    const float* V = vc + (size_t)bh * MAXLEN * HDIM + col4 * 4;

    const float scale = 0.08838834764831845f;   // 1/sqrt(128)
    f32x4 qv = *(const f32x4*)(q + col4 * 4);
    qv *= scale;

    float m = -3.0e38f, l = 0.f;
    f32x4 acc = {0.f, 0.f, 0.f, 0.f};

    // batched online-softmax step over 4 keys (K rows kv[], V rows vv[])
    auto step = [&](const f32x4* kv, const f32x4* vv, float inv0, float inv1,
                    float inv2, float inv3) {
        float s0 = qv.x*kv[0].x + qv.y*kv[0].y + qv.z*kv[0].z + qv.w*kv[0].w;
        float s1 = qv.x*kv[1].x + qv.y*kv[1].y + qv.z*kv[1].z + qv.w*kv[1].w;
        float s2 = qv.x*kv[2].x + qv.y*kv[2].y + qv.z*kv[2].z + qv.w*kv[2].w;
        float s3 = qv.x*kv[3].x + qv.y*kv[3].y + qv.z*kv[3].z + qv.w*kv[3].w;
        #pragma unroll
        for (int off = 16; off > 0; off >>= 1) {
            s0 += __shfl_xor(s0, off, 64);
            s1 += __shfl_xor(s1, off, 64);
            s2 += __shfl_xor(s2, off, 64);
            s3 += __shfl_xor(s3, off, 64);
        }
        s0 += inv0; s1 += inv1; s2 += inv2; s3 += inv3;   // -inf for invalid keys
        float sb = fmaxf(fmaxf(s0, s1), fmaxf(s2, s3));
        float mn = fmaxf(m, sb);
        float corr = __expf(m - mn);
        float p0 = __expf(s0 - mn), p1 = __expf(s1 - mn);
        float p2 = __expf(s2 - mn), p3 = __expf(s3 - mn);
        l = l * corr + ((p0 + p1) + (p2 + p3));
        float tx = fmaf(p3, vv[3].x, fmaf(p2, vv[2].x, fmaf(p1, vv[1].x, p0 * vv[0].x)));
        float ty = fmaf(p3, vv[3].y, fmaf(p2, vv[2].y, fmaf(p1, vv[1].y, p0 * vv[0].y)));
        float tz = fmaf(p3, vv[3].z, fmaf(p2, vv[2].z, fmaf(p1, vv[1].z, p0 * vv[0].z)));
        float tw = fmaf(p3, vv[3].w, fmaf(p2, vv[2].w, fmaf(p1, vv[1].w, p0 * vv[0].w)));
        acc.x = fmaf(acc.x, corr, tx);
        acc.y = fmaf(acc.y, corr, ty);
        acc.z = fmaf(acc.z, corr, tz);
        acc.w = fmaf(acc.w, corr, tw);
        m = mn;
    };

    const bool fast = (len % 32 == 0) && (cl < tstart || cl >= tend);

    if (fast) {
        const int nb = len >> 5;
        if (nb > 0) {
            const int t0 = tstart + g;
            f32x4 kA[4], vA[4], kB[4], vB[4];
            auto ldb = [&](f32x4* kv, f32x4* vv, int tb) {
                #pragma unroll
                for (int u = 0; u < 4; ++u) {
                    kv[u] = *(const f32x4*)(K + (size_t)(tb + u * 8) * HDIM);
                    vv[u] = *(const f32x4*)(V + (size_t)(tb + u * 8) * HDIM);
                }
            };
            ldb(kA, vA, t0);
            int j = 0;
            for (; j + 2 < nb; j += 2) {
                ldb(kB, vB, t0 + (j + 1) * 32);
                step(kA, vA, 0.f, 0.f, 0.f, 0.f);
                ldb(kA, vA, t0 + (j + 2) * 32);
                step(kB, vB, 0.f, 0.f, 0.f, 0.f);
            }
            if (j + 1 < nb) {
                ldb(kB, vB, t0 + (j + 1) * 32);
                step(kA, vA, 0.f, 0.f, 0.f, 0.f);
                step(kB, vB, 0.f, 0.f, 0.f, 0.f);
            } else {
                step(kA, vA, 0.f, 0.f, 0.f, 0.f);
            }
        }
    } else {
        for (int base = tstart + g; base < tend; base += 32) {
            f32x4 kv[4], vv[4];
            float inv[4];
            #pragma unroll
            for (int u = 0; u < 4; ++u) {
                int t = base + u * 8;
                if (t < tend) {
                    const float* kp = (t == cl) ? (knew + col4 * 4) : (K + (size_t)t * HDIM);
                    const float* vp = (t == cl) ? (vnew + col4 * 4) : (V + (size_t)t * HDIM);
                    kv[u] = *(const f32x4*)kp;
                    vv[u] = *(const f32x4*)vp;
                    inv[u] = 0.f;
                } else {
                    kv[u] = f32x4{0.f, 0.f, 0.f, 0.f};
                    vv[u] = f32x4{0.f, 0.f, 0.f, 0.f};
                    inv[u] = -3.0e38f;
                }
            }
            step(kv, vv, inv[0], inv[1], inv[2], inv[3]);
        }
    }

    if (col4 == 0) { mls[g][0] = m; mls[g][1] = l; }
    *(f32x4*)(&accs[g][col4 * 4]) = acc;
    __syncthreads();

    const size_t pidx = (size_t)bh * NSPLIT + sp;
    if (tid < HDIM) {
        float M = mls[0][0];
        #pragma unroll
        for (int i = 1; i < 8; ++i) M = fmaxf(M, mls[i][0]);
        float L = 0.f, o = 0.f;
        #pragma unroll
        for (int i = 0; i < 8; ++i) {
            float wgt = __expf(mls[i][0] - M);
            L += mls[i][1] * wgt;
            o += accs[i][tid] * wgt;
        }
        part_acc[pidx * HDIM + tid] = o;
        if (tid == 0) {
            part_ms[pidx * 2]     = M;
            part_ms[pidx * 2 + 1] = L;
        }
    }
}

__global__ __launch_bounds__(128)
void combine_kernel(const float* __restrict__ part_acc,
                    const float* __restrict__ part_ms,
                    float* __restrict__ attn)
{
    const int bh = blockIdx.x;
    const int d  = threadIdx.x;

    float m[NSPLIT], s[NSPLIT];
    float gmax = -3.0e38f;
    #pragma unroll
    for (int sp = 0; sp < NSPLIT; ++sp) {
        m[sp] = part_ms[((size_t)bh * NSPLIT + sp) * 2];
        s[sp] = part_ms[((size_t)bh * NSPLIT + sp) * 2 + 1];
        gmax  = fmaxf(gmax, m[sp]);
    }
    float total = 0.f, o = 0.f;
    #pragma unroll
    for (int sp = 0; sp < NSPLIT; ++sp) {
        float wgt = __expf(m[sp] - gmax);
        total += s[sp] * wgt;
        o += part_acc[((size_t)bh * NSPLIT + sp) * HDIM + d] * wgt;
    }
    attn[(size_t)bh * HDIM + d] = o / total;
}

extern "C" void kernel_launch(void* const* d_in, const int* in_sizes, int n_in,
                              void* d_out, int out_size, void* d_ws, size_t ws_size,
                              hipStream_t stream) {
    const float* x  = (const float*)d_in[0];
    const float* kc = (const float*)d_in[1];
    const float* vc = (const float*)d_in[2];
    const float* Wq = (const float*)d_in[3];
    const float* bq = (const float*)d_in[4];
    const float* Wk = (const float*)d_in[5];
    const float* bk = (const float*)d_in[6];
    const float* Wv = (const float*)d_in[7];
    const float* bv = (const float*)d_in[8];
    const float* Wo = (const float*)d_in[9];
    const float* bo = (const float*)d_in[10];
    const int* clp  = (const int*)d_in[11];

    float* out      = (float*)d_out;
    float* qkv      = (float*)d_ws;                               // 3*8*4096
    float* attn     = qkv + (size_t)3 * BATCH * EMBED;            // 8*4096
    float* part_acc = attn + (size_t)BATCH * EMBED;               // 256*16*128
    float* part_ms  = part_acc + (size_t)256 * NSPLIT * HDIM;     // 256*16*2

    hipLaunchKernelGGL(qkv_kernel, dim3(768), dim3(256), 0, stream,
                       x, Wq, bq, Wk, bk, Wv, bv, qkv);
    hipLaunchKernelGGL(attn_partial, dim3(256 * NSPLIT), dim3(256), 0, stream,
                       qkv, kc, vc, clp, part_acc, part_ms);
    hipLaunchKernelGGL(combine_kernel, dim3(256), dim3(128), 0, stream,
                       part_acc, part_ms, attn);
    hipLaunchKernelGGL(out_kernel, dim3(512), dim3(256), 0, stream,
                       attn, Wo, bo, out);
}